// Round 1
// 179.314 us; speedup vs baseline: 1.0213x; 1.0213x over previous
//
#include <hip/hip_runtime.h>

typedef unsigned short u16;
typedef unsigned int   u32;
typedef __attribute__((ext_vector_type(8))) short bf16x8;
typedef __attribute__((ext_vector_type(4))) float f32x4;
typedef __attribute__((ext_vector_type(2))) unsigned int u32x2;

__device__ __forceinline__ float bf2f(u16 u) { return __uint_as_float(((u32)u) << 16); }
// round-half-up (ties away): identical to RNE except exact ties; 2 VALU ops.
__device__ __forceinline__ u16 f2bf(float f) {
    return (u16)((__float_as_uint(f) + 0x8000u) >> 16);
}
// packed RNE f32->bf16 pair: one VALU op for two conversions
__device__ __forceinline__ u32 cvt_pk_bf16(float lo, float hi) {
    u32 r;
    asm("v_cvt_pk_bf16_f32 %0, %1, %2" : "=v"(r) : "v"(lo), "v"(hi));
    return r;
}
__device__ __forceinline__ void gload16(const void* g, void* l) {
    __builtin_amdgcn_global_load_lds((const __attribute__((address_space(1))) void*)g,
                                     (__attribute__((address_space(3))) void*)l, 16, 0, 0);
}

// ---------------------------------------------------------------------------
// Fused fp32->bf16 conversion for hs + Wq + Wk + Wv (contiguous dsts in ws).
// ---------------------------------------------------------------------------
struct us4 { u16 x, y, z, w; };
__global__ void cvt_all(const float* __restrict__ hs, const float* __restrict__ wq,
                        const float* __restrict__ wk, const float* __restrict__ wv,
                        u16* __restrict__ dst)
{
    int i = blockIdx.x * blockDim.x + threadIdx.x;
    const int stride = gridDim.x * blockDim.x;
    us4* d4 = (us4*)dst;
    for (; i < 1835008; i += stride) {
        const float4* s4;
        int j = i;
        if (j < 1048576)      { s4 = (const float4*)hs; }
        else if (j < 1310720) { s4 = (const float4*)wq; j -= 1048576; }
        else if (j < 1572864) { s4 = (const float4*)wk; j -= 1310720; }
        else                  { s4 = (const float4*)wv; j -= 1572864; }
        float4 v = s4[j];
        us4 o;
        o.x = f2bf(v.x); o.y = f2bf(v.y); o.z = f2bf(v.z); o.w = f2bf(v.w);
        d4[i] = o;
    }
}

// ---------------------------------------------------------------------------
// Kernel 1: fused QKV projection (unchanged).  64x128 tile, BK=64,
// grid 64x24 = 1536 blocks = 6/CU.  Q,K out [b,h,n,d]; V out transposed.
// ---------------------------------------------------------------------------
__global__ __launch_bounds__(256) void qkv_gemm(
    const u16* __restrict__ hs,
    const u16* __restrict__ Wq, const u16* __restrict__ Wk, const u16* __restrict__ Wv,
    const float* __restrict__ bq, const float* __restrict__ bk, const float* __restrict__ bv,
    u16* __restrict__ oq, u16* __restrict__ ok, u16* __restrict__ ovt)
{
    __shared__ u16 smem[12288];        // sA 64x64 [0,4096), sB 128x64 [4096,12288)
    u16* sA = smem;
    u16* sB = smem + 4096;

    const int tid  = threadIdx.x;
    const int lane = tid & 63;
    const int wv_  = tid >> 6;
    const int c15  = lane & 15;
    const int q4   = lane >> 4;
    const int rb   = blockIdx.x;        // row block 0..63 (64 rows)
    const int mat  = blockIdx.y >> 3;   // 0=q 1=k 2=v
    const int cb   = blockIdx.y & 7;    // col block 0..7 (128 cols)

    const u16*   W    = (mat == 0) ? Wq : (mat == 1 ? Wk : Wv);
    const float* bias = (mat == 0) ? bq : (mat == 1 ? bk : bv);

    f32x4 acc[4][2] = {};

    int rA[2], cA[2], rB[4], cB[4];
#pragma unroll
    for (int p = 0; p < 2; ++p) {
        const int ch = p * 256 + tid;
        rA[p] = ch >> 3; cA[p] = ((ch & 7) ^ (rA[p] & 7)) * 8;
    }
#pragma unroll
    for (int p = 0; p < 4; ++p) {
        const int ch = p * 256 + tid;
        rB[p] = ch >> 3; cB[p] = ((ch & 7) ^ (rB[p] & 7)) * 8;
    }
    const u16* gA = hs + (rb * 64) * 1024;
    const u16* gB = W + (cb * 128) * 1024;
    const int swz = c15 & 7;

    for (int kb = 0; kb < 1024; kb += 64) {
        __syncthreads();
#pragma unroll
        for (int p = 0; p < 2; ++p)
            gload16(gA + rA[p] * 1024 + kb + cA[p], sA + (p * 256 + wv_ * 64) * 8);
#pragma unroll
        for (int p = 0; p < 4; ++p)
            gload16(gB + rB[p] * 1024 + kb + cB[p], sB + (p * 256 + wv_ * 64) * 8);
        __syncthreads();

#pragma unroll
        for (int kk = 0; kk < 2; ++kk) {
            const int cpos = ((kk * 4 + q4) ^ swz) * 8;
            bf16x8 af[4], bf[2];
#pragma unroll
            for (int mt = 0; mt < 4; ++mt)
                af[mt] = *(const bf16x8*)(sA + (mt * 16 + c15) * 64 + cpos);
#pragma unroll
            for (int nt = 0; nt < 2; ++nt)
                bf[nt] = *(const bf16x8*)(sB + (wv_ * 32 + nt * 16 + c15) * 64 + cpos);
#pragma unroll
            for (int mt = 0; mt < 4; ++mt)
#pragma unroll
                for (int nt = 0; nt < 2; ++nt)
                    acc[mt][nt] = __builtin_amdgcn_mfma_f32_16x16x32_bf16(
                        af[mt], bf[nt], acc[mt][nt], 0, 0, 0);
        }
    }

    // ---- epilogue: bias add, per-wave LDS transpose, coalesced 16B stores ----
    __syncthreads();
    const int hcol = cb * 2 + (wv_ >> 1);
    const int dbase = (wv_ & 1) * 32;
    float bvv[2];
#pragma unroll
    for (int nt = 0; nt < 2; ++nt)
        bvv[nt] = bias[cb * 128 + wv_ * 32 + nt * 16 + c15];

    u16* sc = smem + wv_ * 2560;
    if (mat != 2) {
        u16* dst = (mat == 0) ? oq : ok;
#pragma unroll
        for (int mt = 0; mt < 4; ++mt)
#pragma unroll
            for (int nt = 0; nt < 2; ++nt)
#pragma unroll
                for (int r = 0; r < 4; ++r)
                    sc[(mt * 16 + q4 * 4 + r) * 40 + nt * 16 + c15] =
                        f2bf(acc[mt][nt][r] + bvv[nt]);
#pragma unroll
        for (int i = 0; i < 4; ++i) {
            const int rl = i * 16 + (lane >> 2);
            const int c0 = (lane & 3) * 8;
            bf16x8 vv = *(const bf16x8*)(sc + rl * 40 + c0);
            const int n = rb * 64 + rl;
            const int bb = n >> 11, nn = n & 2047;
            *(bf16x8*)(dst + (((bb * 16 + hcol) * 2048) + nn) * 64 + dbase + c0) = vv;
        }
    } else {
#pragma unroll
        for (int mt = 0; mt < 4; ++mt)
#pragma unroll
            for (int nt = 0; nt < 2; ++nt)
#pragma unroll
                for (int r = 0; r < 4; ++r)
                    sc[(nt * 16 + c15) * 72 + mt * 16 + q4 * 4 + r] =
                        f2bf(acc[mt][nt][r] + bvv[nt]);
#pragma unroll
        for (int i = 0; i < 4; ++i) {
            const int dp = i * 8 + (lane >> 3);
            const int nl = (lane & 7) * 8;
            bf16x8 vv = *(const bf16x8*)(sc + dp * 72 + nl);
            const int n = rb * 64 + nl;
            const int bb = n >> 11, nn = n & 2047;
            *(bf16x8*)(ovt + (((bb * 16 + hcol) * 64) + dbase + dp) * 2048 + nn) = vv;
        }
    }
}

// ---------------------------------------------------------------------------
// Kernel 2: flash attention, S^T formulation, in-register P, FULL-K32 PV.
// R9 changes vs R8-best:
//   * 8 waves / 512 threads per block, wave owns 16 q-rows (rt loop removed).
//     Grid stays (16,32) -> 2 blocks/CU x 8 waves = 16 waves/CU (was 8):
//     doubles wave-level overlap of the QK^T->softmax->PV dependency chain
//     with NO extra K/V staging (512 threads stage the same two 64x64 tiles,
//     1 chunk each).
//   * PERMUTED key order in sK: staging row rho holds real key
//       perm(rho) = (rho&0x23) | ((rho&0x0C)<<1) | ((rho&0x10)>>2)
//     i.e. key = 32*(t>>1) + 8*q4 + 4*(t&1) + r for rho = t*16+q4*4+r.
//     After softmax, the packed P registers [t=2g r0..3 | t=2g+1 r0..3] of
//     lane-group q4 are real keys 32g+8*q4 .. 32g+8*q4+7 — CONSECUTIVE — so
//     each PV B-fragment is ONE ds_read_b128 from sVT (was 2x ds_read_b64):
//     8 V-reads/iter instead of 16.  Mask addressing follows the same order
//     (still aligned float4 loads); softmax is key-order-invariant.
//   * softmax VALU trim: exp2 with 0.125*log2e folded into the fma (mask
//     pre-scaled by log2e), and v_cvt_pk_bf16_f32 packs each f32 pair in one
//     op (was 5-op bit trick).
// Per wave-iter: 8 ds_read_b128 (K) + 8 ds_read_b128 (V), 16 MFMA.
// ---------------------------------------------------------------------------
__global__ __launch_bounds__(512, 4) void attn(
    const u16* __restrict__ qm, const u16* __restrict__ km, const u16* __restrict__ vtm,
    const float* __restrict__ mask, float* __restrict__ out)
{
    __shared__ u16 sK[64 * 64];        // [rho=permuted key][d-chunk], XOR-swizzled by rho&7
    __shared__ u16 sVT[64 * 64];       // [d][key-chunk] (real key order), XOR-swizzled by d&7

    const int tid = threadIdx.x, lane = tid & 63, w = tid >> 6;
    const int c15 = lane & 15, q4 = lane >> 4;
    const int qt = blockIdx.x;         // q tile 0..15 (128 rows each)
    const int bh = blockIdx.y;         // 0..31
    const int b = bh >> 4;

    // Q fragments (B operand of S^T = K.Q^T): Q[qrow=c15][d=kt*32+q4*8+j]
    bf16x8 qf[2];
    const u16* qbase = qm + (bh * 2048 + qt * 128 + w * 16) * 64;
#pragma unroll
    for (int kt = 0; kt < 2; ++kt)
        qf[kt] = *(const bf16x8*)(qbase + c15 * 64 + kt * 32 + q4 * 8);

    float l_acc = 0.f;
    f32x4 accO[4] = {};

    const u16* kbase  = km  + bh * 2048 * 64;
    const u16* vtbase = vtm + bh * 64 * 2048;   // [d][n]

    // staging: each 64x64 tile = 512 16B chunks, 1 per thread
    const int r  = tid >> 3;                    // dest row 0..63
    const int cc = tid & 7;                     // dest chunk-col
    const int col = (cc ^ (r & 7)) * 8;         // XOR-swizzled source col (u16)
    const int pr  = (r & 0x23) | ((r & 0x0C) << 1) | ((r & 0x10) >> 2);  // perm key
    const int offK = pr * 64 + col;             // key-permuted K source offset
    const int offV = r * 2048 + col;            // V^T source offset (d-major)
    u16* dstK = sK  + w * 512;                  // wave-uniform LDS dest (lane*16B appended)
    u16* dstV = sVT + w * 512;

    const float* mbase = mask + b * 2048 + 8 * q4;

    for (int it = 0; it < 32; ++it) {
        const int kb = it * 64;
        __syncthreads();               // prior iter's sK/sVT reads done

        gload16(kbase + kb * 64 + offK, dstK);  // K  [perm key][d]
        gload16(vtbase + kb + offV, dstV);      // V^T [d][key]
        __syncthreads();               // staging resident

        // mask per key, pre-scaled by log2e.  Element (t,rr) <-> real key
        // kb + 32*(t>>1) + 8*q4 + 4*(t&1) + rr  (aligned float4 per t).
        float mkv[4][4];
#pragma unroll
        for (int t = 0; t < 4; ++t) {
            float4 m4 = *(const float4*)(mbase + kb + 32 * (t >> 1) + 4 * (t & 1));
            mkv[t][0] = m4.x * 1.4426950408889634f;
            mkv[t][1] = m4.y * 1.4426950408889634f;
            mkv[t][2] = m4.z * 1.4426950408889634f;
            mkv[t][3] = m4.w * 1.4426950408889634f;
        }

        // --- S^T = K Q^T: D[rho][qrow]; lane(q4,c15) reg rr = S[rho=t*16+q4*4+rr][c15]
        f32x4 accST[4] = {};
#pragma unroll
        for (int kt = 0; kt < 2; ++kt) {
            bf16x8 kf[4];
#pragma unroll
            for (int t = 0; t < 4; ++t) {
                const int rho = t * 16 + c15;
                const int cpos = (kt * 4 + q4) ^ (rho & 7);
                kf[t] = *(const bf16x8*)(sK + rho * 64 + cpos * 8);
            }
#pragma unroll
            for (int t = 0; t < 4; ++t)
                accST[t] = __builtin_amdgcn_mfma_f32_16x16x32_bf16(
                    kf[t], qf[kt], accST[t], 0, 0, 0);
        }

        // --- softmax in-register: p = exp2(s*0.125*log2e + m*log2e); pack pairs
        u32 pu[4][2];
#pragma unroll
        for (int t = 0; t < 4; ++t) {
            float p[4];
#pragma unroll
            for (int rr = 0; rr < 4; ++rr) {
                p[rr] = __builtin_amdgcn_exp2f(
                    fmaf(accST[t][rr], 0.18033688011112042f, mkv[t][rr]));
                l_acc += p[rr];
            }
            pu[t][0] = cvt_pk_bf16(p[0], p[1]);
            pu[t][1] = cvt_pk_bf16(p[2], p[3]);
        }

        // --- PV full-K32: A-frag of lane-group q4 = real keys 32g+8q4..+7
#pragma unroll
        for (int g = 0; g < 2; ++g) {
            union { bf16x8 v; u32 u[4]; } ta;
            ta.u[0] = pu[2 * g][0];
            ta.u[1] = pu[2 * g][1];
            ta.u[2] = pu[2 * g + 1][0];
            ta.u[3] = pu[2 * g + 1][1];
            // B-frags: V[keys 32g+8q4..+7][d=nt*16+c15] = one b128 per nt
            bf16x8 vB[4];
#pragma unroll
            for (int nt = 0; nt < 4; ++nt) {
                const int d = nt * 16 + c15;
                const int pc = (4 * g + q4) ^ (d & 7);
                vB[nt] = *(const bf16x8*)(sVT + d * 64 + pc * 8);
            }
#pragma unroll
            for (int nt = 0; nt < 4; ++nt)
                accO[nt] = __builtin_amdgcn_mfma_f32_16x16x32_bf16(
                    ta.v, vB[nt], accO[nt], 0, 0, 0);
        }
    }

    // --- l reduction across q4 groups -> total per qrow=c15
    l_acc += __shfl_xor(l_acc, 16);
    l_acc += __shfl_xor(l_acc, 32);

    // --- epilogue: accO C-layout row=q4*4+rr=qrow-local, col=c15=d
    const int h = bh & 15;
    float inv[4];
#pragma unroll
    for (int rr = 0; rr < 4; ++rr)
        inv[rr] = 1.0f / __shfl(l_acc, q4 * 4 + rr);
#pragma unroll
    for (int nt = 0; nt < 4; ++nt)
#pragma unroll
        for (int rr = 0; rr < 4; ++rr) {
            const int qrow = qt * 128 + w * 16 + q4 * 4 + rr;
            const int d = nt * 16 + c15;
            out[(b * 2048 + qrow) * 1024 + h * 64 + d] = accO[nt][rr] * inv[rr];
        }
}

// ---------------------------------------------------------------------------
extern "C" void kernel_launch(void* const* d_in, const int* in_sizes, int n_in,
                              void* d_out, int out_size, void* d_ws, size_t ws_size,
                              hipStream_t stream)
{
    const float* hs   = (const float*)d_in[0];
    const float* mask = (const float*)d_in[1];
    const float* Wq   = (const float*)d_in[2];
    const float* bq   = (const float*)d_in[3];
    const float* Wk   = (const float*)d_in[4];
    const float* bk   = (const float*)d_in[5];
    const float* Wv   = (const float*)d_in[6];
    const float* bv   = (const float*)d_in[7];

    // workspace layout (u16 units)
    u16* ws   = (u16*)d_ws;
    u16* qw   = ws;                     // Q  [b,h,n,d] bf16
    u16* kw   = ws + 4194304;           // K  [b,h,n,d]
    u16* vtw  = ws + 8388608;           // V^T [b,h,d,n]
    u16* hsb  = ws + 12582912;          // hidden_states bf16 (cvt_all dst start)
    u16* wqb  = ws + 16777216;
    u16* wkb  = ws + 17825792;
    u16* wvb  = ws + 18874368;

    cvt_all<<<1024, 256, 0, stream>>>(hs, Wq, Wk, Wv, hsb);

    qkv_gemm<<<dim3(64, 24), 256, 0, stream>>>(hsb, wqb, wkb, wvb, bq, bk, bv, qw, kw, vtw);
    attn<<<dim3(16, 32), 512, 0, stream>>>(qw, kw, vtw, mask, (float*)d_out);
}

// Round 2
// 177.911 us; speedup vs baseline: 1.0294x; 1.0079x over previous
//
#include <hip/hip_runtime.h>

typedef unsigned short u16;
typedef unsigned int   u32;
typedef __attribute__((ext_vector_type(8))) short bf16x8;
typedef __attribute__((ext_vector_type(4))) float f32x4;
typedef __attribute__((ext_vector_type(2))) unsigned int u32x2;

__device__ __forceinline__ float bf2f(u16 u) { return __uint_as_float(((u32)u) << 16); }
// round-half-up (ties away): identical to RNE except exact ties; 2 VALU ops.
__device__ __forceinline__ u16 f2bf(float f) {
    return (u16)((__float_as_uint(f) + 0x8000u) >> 16);
}
// packed RNE f32->bf16 pair: one VALU op for two conversions
__device__ __forceinline__ u32 cvt_pk_bf16(float lo, float hi) {
    u32 r;
    asm("v_cvt_pk_bf16_f32 %0, %1, %2" : "=v"(r) : "v"(lo), "v"(hi));
    return r;
}
__device__ __forceinline__ void gload16(const void* g, void* l) {
    __builtin_amdgcn_global_load_lds((const __attribute__((address_space(1))) void*)g,
                                     (__attribute__((address_space(3))) void*)l, 16, 0, 0);
}

// ---------------------------------------------------------------------------
// Fused fp32->bf16 conversion for hs + Wq + Wk + Wv (contiguous dsts in ws).
// ---------------------------------------------------------------------------
struct us4 { u16 x, y, z, w; };
__global__ void cvt_all(const float* __restrict__ hs, const float* __restrict__ wq,
                        const float* __restrict__ wk, const float* __restrict__ wv,
                        u16* __restrict__ dst)
{
    int i = blockIdx.x * blockDim.x + threadIdx.x;
    const int stride = gridDim.x * blockDim.x;
    us4* d4 = (us4*)dst;
    for (; i < 1835008; i += stride) {
        const float4* s4;
        int j = i;
        if (j < 1048576)      { s4 = (const float4*)hs; }
        else if (j < 1310720) { s4 = (const float4*)wq; j -= 1048576; }
        else if (j < 1572864) { s4 = (const float4*)wk; j -= 1310720; }
        else                  { s4 = (const float4*)wv; j -= 1572864; }
        float4 v = s4[j];
        us4 o;
        o.x = f2bf(v.x); o.y = f2bf(v.y); o.z = f2bf(v.z); o.w = f2bf(v.w);
        d4[i] = o;
    }
}

// ---------------------------------------------------------------------------
// Kernel 1: fused QKV projection (unchanged).  64x128 tile, BK=64,
// grid 64x24 = 1536 blocks = 6/CU.  Q,K out [b,h,n,d]; V out transposed.
// ---------------------------------------------------------------------------
__global__ __launch_bounds__(256) void qkv_gemm(
    const u16* __restrict__ hs,
    const u16* __restrict__ Wq, const u16* __restrict__ Wk, const u16* __restrict__ Wv,
    const float* __restrict__ bq, const float* __restrict__ bk, const float* __restrict__ bv,
    u16* __restrict__ oq, u16* __restrict__ ok, u16* __restrict__ ovt)
{
    __shared__ u16 smem[12288];        // sA 64x64 [0,4096), sB 128x64 [4096,12288)
    u16* sA = smem;
    u16* sB = smem + 4096;

    const int tid  = threadIdx.x;
    const int lane = tid & 63;
    const int wv_  = tid >> 6;
    const int c15  = lane & 15;
    const int q4   = lane >> 4;
    const int rb   = blockIdx.x;        // row block 0..63 (64 rows)
    const int mat  = blockIdx.y >> 3;   // 0=q 1=k 2=v
    const int cb   = blockIdx.y & 7;    // col block 0..7 (128 cols)

    const u16*   W    = (mat == 0) ? Wq : (mat == 1 ? Wk : Wv);
    const float* bias = (mat == 0) ? bq : (mat == 1 ? bk : bv);

    f32x4 acc[4][2] = {};

    int rA[2], cA[2], rB[4], cB[4];
#pragma unroll
    for (int p = 0; p < 2; ++p) {
        const int ch = p * 256 + tid;
        rA[p] = ch >> 3; cA[p] = ((ch & 7) ^ (rA[p] & 7)) * 8;
    }
#pragma unroll
    for (int p = 0; p < 4; ++p) {
        const int ch = p * 256 + tid;
        rB[p] = ch >> 3; cB[p] = ((ch & 7) ^ (rB[p] & 7)) * 8;
    }
    const u16* gA = hs + (rb * 64) * 1024;
    const u16* gB = W + (cb * 128) * 1024;
    const int swz = c15 & 7;

    for (int kb = 0; kb < 1024; kb += 64) {
        __syncthreads();
#pragma unroll
        for (int p = 0; p < 2; ++p)
            gload16(gA + rA[p] * 1024 + kb + cA[p], sA + (p * 256 + wv_ * 64) * 8);
#pragma unroll
        for (int p = 0; p < 4; ++p)
            gload16(gB + rB[p] * 1024 + kb + cB[p], sB + (p * 256 + wv_ * 64) * 8);
        __syncthreads();

#pragma unroll
        for (int kk = 0; kk < 2; ++kk) {
            const int cpos = ((kk * 4 + q4) ^ swz) * 8;
            bf16x8 af[4], bf[2];
#pragma unroll
            for (int mt = 0; mt < 4; ++mt)
                af[mt] = *(const bf16x8*)(sA + (mt * 16 + c15) * 64 + cpos);
#pragma unroll
            for (int nt = 0; nt < 2; ++nt)
                bf[nt] = *(const bf16x8*)(sB + (wv_ * 32 + nt * 16 + c15) * 64 + cpos);
#pragma unroll
            for (int mt = 0; mt < 4; ++mt)
#pragma unroll
                for (int nt = 0; nt < 2; ++nt)
                    acc[mt][nt] = __builtin_amdgcn_mfma_f32_16x16x32_bf16(
                        af[mt], bf[nt], acc[mt][nt], 0, 0, 0);
        }
    }

    // ---- epilogue: bias add, per-wave LDS transpose, coalesced 16B stores ----
    __syncthreads();
    const int hcol = cb * 2 + (wv_ >> 1);
    const int dbase = (wv_ & 1) * 32;
    float bvv[2];
#pragma unroll
    for (int nt = 0; nt < 2; ++nt)
        bvv[nt] = bias[cb * 128 + wv_ * 32 + nt * 16 + c15];

    u16* sc = smem + wv_ * 2560;
    if (mat != 2) {
        u16* dst = (mat == 0) ? oq : ok;
#pragma unroll
        for (int mt = 0; mt < 4; ++mt)
#pragma unroll
            for (int nt = 0; nt < 2; ++nt)
#pragma unroll
                for (int r = 0; r < 4; ++r)
                    sc[(mt * 16 + q4 * 4 + r) * 40 + nt * 16 + c15] =
                        f2bf(acc[mt][nt][r] + bvv[nt]);
#pragma unroll
        for (int i = 0; i < 4; ++i) {
            const int rl = i * 16 + (lane >> 2);
            const int c0 = (lane & 3) * 8;
            bf16x8 vv = *(const bf16x8*)(sc + rl * 40 + c0);
            const int n = rb * 64 + rl;
            const int bb = n >> 11, nn = n & 2047;
            *(bf16x8*)(dst + (((bb * 16 + hcol) * 2048) + nn) * 64 + dbase + c0) = vv;
        }
    } else {
#pragma unroll
        for (int mt = 0; mt < 4; ++mt)
#pragma unroll
            for (int nt = 0; nt < 2; ++nt)
#pragma unroll
                for (int r = 0; r < 4; ++r)
                    sc[(nt * 16 + c15) * 72 + mt * 16 + q4 * 4 + r] =
                        f2bf(acc[mt][nt][r] + bvv[nt]);
#pragma unroll
        for (int i = 0; i < 4; ++i) {
            const int dp = i * 8 + (lane >> 3);
            const int nl = (lane & 7) * 8;
            bf16x8 vv = *(const bf16x8*)(sc + dp * 72 + nl);
            const int n = rb * 64 + nl;
            const int bb = n >> 11, nn = n & 2047;
            *(bf16x8*)(ovt + (((bb * 16 + hcol) * 64) + dbase + dp) * 2048 + nn) = vv;
        }
    }
}

// ---------------------------------------------------------------------------
// Kernel 2: flash attention, S^T formulation, in-register P, FULL-K32 PV.
// R2 changes vs R1:
//   * Qw=32: wave owns 32 q-rows again (rt=2 accumulator pair, 256-thread /
//     4-wave blocks, grid (16,32) -> 2 blocks/CU).  K-frags, V-frags and mask
//     are all shared across rt, so LDS reads stay 16 b128/wave-iter while
//     MFMA doubles to 32 -> LDS read traffic HALVES (2.1 GB -> 1.05 GB,
//     ~40 us -> ~20 us of LDS-pipe demand).  R1's counters showed MfmaUtil
//     pinned at 20% with VALU 35%, HBM 16%, conflicts 0: the wall was LDS
//     bandwidth + exposed global-load latency, not VALU and not occupancy.
//   * Double-buffered K/V with ONE barrier per iteration (T3 2-phase):
//     stage tile t+1 into the other buffer BEFORE computing tile t; the
//     end-of-iteration __syncthreads (compiler drains vmcnt there) makes the
//     prefetched tile resident.  Load latency hides under 32 MFMA + softmax.
//     Distinct static LDS arrays + unroll-by-2 body keep the compiler from
//     inserting an alias-driven vmcnt(0) before the ds_reads.
//   * Mask stays in GLOBAL (L1/L2-served, vector-mem pipe) — deliberately
//     NOT staged in LDS, the LDS pipe is the scarce resource.
// Per wave-iter: 8 ds_read_b128 (K) + 8 ds_read_b128 (V), 32 MFMA.
// ---------------------------------------------------------------------------
__global__ __launch_bounds__(256, 2) void attn(
    const u16* __restrict__ qm, const u16* __restrict__ km, const u16* __restrict__ vtm,
    const float* __restrict__ mask, float* __restrict__ out)
{
    __shared__ u16 sK0[4096];          // [rho=permuted key][d-chunk], XOR-swizzled
    __shared__ u16 sV0[4096];          // [d][key-chunk], XOR-swizzled
    __shared__ u16 sK1[4096];
    __shared__ u16 sV1[4096];

    const int tid = threadIdx.x, lane = tid & 63, w = tid >> 6;
    const int c15 = lane & 15, q4 = lane >> 4;
    const int qt = blockIdx.x;         // q tile 0..15 (128 rows each)
    const int bh = blockIdx.y;         // 0..31
    const int b = bh >> 4;

    // Q fragments (B operand of S^T = K.Q^T): rows qt*128 + w*32 + rt*16 + c15
    bf16x8 qf[2][2];
    const u16* qbase = qm + (bh * 2048 + qt * 128 + w * 32) * 64;
#pragma unroll
    for (int rt = 0; rt < 2; ++rt)
#pragma unroll
        for (int kt = 0; kt < 2; ++kt)
            qf[rt][kt] = *(const bf16x8*)(qbase + (rt * 16 + c15) * 64 + kt * 32 + q4 * 8);

    float l_acc[2] = {0.f, 0.f};
    f32x4 accO[2][4] = {};

    const u16* kbase  = km  + bh * 2048 * 64;
    const u16* vtbase = vtm + bh * 64 * 2048;   // [d][n]

    // staging: each 64x64 tile = 512 16B chunks, 2 per thread (p=0,1)
    const int row0 = tid >> 3;                  // dest row 0..31 (p adds 32)
    const int col  = ((tid & 7) ^ (row0 & 7)) * 8;   // XOR-swizzled col (u16)
    const int pr0  = (row0 & 0x23) | ((row0 & 0x0C) << 1) | ((row0 & 0x10) >> 2);
    const int kOff0 = pr0 * 64 + col;           // K src (perm key row), p=0
    const int kOff1 = kOff0 + 32 * 64;          // p=1: perm(row+32)=perm(row)+32
    const int vOff0 = row0 * 2048 + col;        // V^T src (d-major), p=0
    const int vOff1 = vOff0 + 32 * 2048;
    const int ldsOff0 = (w * 64) * 8;           // wave-uniform LDS dests
    const int ldsOff1 = (256 + w * 64) * 8;

    const float* mbase = mask + b * 2048 + 8 * q4;

    // ---- compute one 64-key tile from the given buffers ----
    auto compute = [&](const u16* sK, const u16* sVT, int kb) {
        // mask per key, pre-scaled by log2e.  (t,rr) <-> real key
        // kb + 32*(t>>1) + 8*q4 + 4*(t&1) + rr  (aligned float4 per t).
        float mkv[4][4];
#pragma unroll
        for (int t = 0; t < 4; ++t) {
            float4 m4 = *(const float4*)(mbase + kb + 32 * (t >> 1) + 4 * (t & 1));
            mkv[t][0] = m4.x * 1.4426950408889634f;
            mkv[t][1] = m4.y * 1.4426950408889634f;
            mkv[t][2] = m4.z * 1.4426950408889634f;
            mkv[t][3] = m4.w * 1.4426950408889634f;
        }

        // --- S^T = K Q^T: lane(q4,c15) reg rr = S[rho=t*16+q4*4+rr][rt*16+c15]
        f32x4 accST[4][2] = {};
#pragma unroll
        for (int kt = 0; kt < 2; ++kt) {
            bf16x8 kf[4];
#pragma unroll
            for (int t = 0; t < 4; ++t) {
                const int rho = t * 16 + c15;
                const int cpos = (kt * 4 + q4) ^ (rho & 7);
                kf[t] = *(const bf16x8*)(sK + rho * 64 + cpos * 8);
            }
#pragma unroll
            for (int t = 0; t < 4; ++t)
#pragma unroll
                for (int rt = 0; rt < 2; ++rt)
                    accST[t][rt] = __builtin_amdgcn_mfma_f32_16x16x32_bf16(
                        kf[t], qf[rt][kt], accST[t][rt], 0, 0, 0);
        }

        // --- softmax in-register: p = exp2(s*0.125*log2e + m*log2e)
        u32 pu[4][2][2];
#pragma unroll
        for (int t = 0; t < 4; ++t)
#pragma unroll
            for (int rt = 0; rt < 2; ++rt) {
                float p[4];
#pragma unroll
                for (int rr = 0; rr < 4; ++rr) {
                    p[rr] = __builtin_amdgcn_exp2f(
                        fmaf(accST[t][rt][rr], 0.18033688011112042f, mkv[t][rr]));
                    l_acc[rt] += p[rr];
                }
                pu[t][rt][0] = cvt_pk_bf16(p[0], p[1]);
                pu[t][rt][1] = cvt_pk_bf16(p[2], p[3]);
            }

        // --- PV full-K32: A-frag of lane-group q4 = real keys 32g+8q4..+7
#pragma unroll
        for (int g = 0; g < 2; ++g) {
            // B-frags shared across rt: V[keys 32g+8q4..+7][d=nt*16+c15]
            bf16x8 vB[4];
#pragma unroll
            for (int nt = 0; nt < 4; ++nt) {
                const int d = nt * 16 + c15;
                const int pc = (4 * g + q4) ^ (d & 7);
                vB[nt] = *(const bf16x8*)(sVT + d * 64 + pc * 8);
            }
#pragma unroll
            for (int rt = 0; rt < 2; ++rt) {
                union { bf16x8 v; u32 u[4]; } ta;
                ta.u[0] = pu[2 * g][rt][0];
                ta.u[1] = pu[2 * g][rt][1];
                ta.u[2] = pu[2 * g + 1][rt][0];
                ta.u[3] = pu[2 * g + 1][rt][1];
#pragma unroll
                for (int nt = 0; nt < 4; ++nt)
                    accO[rt][nt] = __builtin_amdgcn_mfma_f32_16x16x32_bf16(
                        ta.v, vB[nt], accO[rt][nt], 0, 0, 0);
            }
        }
    };

    // ---- prologue: stage tile 0 -> buf0 ----
    gload16(kbase + kOff0, sK0 + ldsOff0);
    gload16(kbase + kOff1, sK0 + ldsOff1);
    gload16(vtbase + vOff0, sV0 + ldsOff0);
    gload16(vtbase + vOff1, sV0 + ldsOff1);
    __syncthreads();

    // ---- main loop: unrolled by 2 (buffers are distinct static arrays) ----
#pragma unroll 1
    for (int it = 0; it < 32; it += 2) {
        {   // stage tile it+1 -> buf1 (it+1 <= 31 always)
            const int kb = (it + 1) * 64;
            gload16(kbase + kb * 64 + kOff0, sK1 + ldsOff0);
            gload16(kbase + kb * 64 + kOff1, sK1 + ldsOff1);
            gload16(vtbase + kb + vOff0, sV1 + ldsOff0);
            gload16(vtbase + kb + vOff1, sV1 + ldsOff1);
        }
        compute(sK0, sV0, it * 64);
        __syncthreads();               // buf1 resident; buf0 reads done

        if (it + 2 < 32) {             // stage tile it+2 -> buf0
            const int kb = (it + 2) * 64;
            gload16(kbase + kb * 64 + kOff0, sK0 + ldsOff0);
            gload16(kbase + kb * 64 + kOff1, sK0 + ldsOff1);
            gload16(vtbase + kb + vOff0, sV0 + ldsOff0);
            gload16(vtbase + kb + vOff1, sV0 + ldsOff1);
        }
        compute(sK1, sV1, (it + 1) * 64);
        __syncthreads();               // buf0 resident; buf1 reads done
    }

    // --- l reduction across q4 groups -> total per qrow=c15
#pragma unroll
    for (int rt = 0; rt < 2; ++rt) {
        l_acc[rt] += __shfl_xor(l_acc[rt], 16);
        l_acc[rt] += __shfl_xor(l_acc[rt], 32);
    }

    // --- epilogue: accO C-layout row=q4*4+rr, col=c15=d
    const int h = bh & 15;
#pragma unroll
    for (int rt = 0; rt < 2; ++rt) {
        float inv[4];
#pragma unroll
        for (int rr = 0; rr < 4; ++rr)
            inv[rr] = 1.0f / __shfl(l_acc[rt], q4 * 4 + rr);
#pragma unroll
        for (int nt = 0; nt < 4; ++nt)
#pragma unroll
            for (int rr = 0; rr < 4; ++rr) {
                const int qrow = qt * 128 + w * 32 + rt * 16 + q4 * 4 + rr;
                const int d = nt * 16 + c15;
                out[(b * 2048 + qrow) * 1024 + h * 64 + d] = accO[rt][nt][rr] * inv[rr];
            }
    }
}

// ---------------------------------------------------------------------------
extern "C" void kernel_launch(void* const* d_in, const int* in_sizes, int n_in,
                              void* d_out, int out_size, void* d_ws, size_t ws_size,
                              hipStream_t stream)
{
    const float* hs   = (const float*)d_in[0];
    const float* mask = (const float*)d_in[1];
    const float* Wq   = (const float*)d_in[2];
    const float* bq   = (const float*)d_in[3];
    const float* Wk   = (const float*)d_in[4];
    const float* bk   = (const float*)d_in[5];
    const float* Wv   = (const float*)d_in[6];
    const float* bv   = (const float*)d_in[7];

    // workspace layout (u16 units)
    u16* ws   = (u16*)d_ws;
    u16* qw   = ws;                     // Q  [b,h,n,d] bf16
    u16* kw   = ws + 4194304;           // K  [b,h,n,d]
    u16* vtw  = ws + 8388608;           // V^T [b,h,d,n]
    u16* hsb  = ws + 12582912;          // hidden_states bf16 (cvt_all dst start)
    u16* wqb  = ws + 16777216;
    u16* wkb  = ws + 17825792;
    u16* wvb  = ws + 18874368;

    cvt_all<<<1024, 256, 0, stream>>>(hs, Wq, Wk, Wv, hsb);

    qkv_gemm<<<dim3(64, 24), 256, 0, stream>>>(hsb, wqb, wkb, wvb, bq, bk, bv, qw, kw, vtw);
    attn<<<dim3(16, 32), 256, 0, stream>>>(qw, kw, vtw, mask, (float*)d_out);
}

// Round 4
// 165.959 us; speedup vs baseline: 1.1035x; 1.0720x over previous
//
#include <hip/hip_runtime.h>

typedef unsigned short u16;
typedef unsigned int   u32;
typedef __attribute__((ext_vector_type(8))) short bf16x8;
typedef __attribute__((ext_vector_type(4))) float f32x4;
typedef __attribute__((ext_vector_type(2))) unsigned int u32x2;

__device__ __forceinline__ float bf2f(u16 u) { return __uint_as_float(((u32)u) << 16); }
// round-half-up (ties away): identical to RNE except exact ties; 2 VALU ops.
__device__ __forceinline__ u16 f2bf(float f) {
    return (u16)((__float_as_uint(f) + 0x8000u) >> 16);
}
// packed RNE f32->bf16 pair: one VALU op for two conversions
__device__ __forceinline__ u32 cvt_pk_bf16(float lo, float hi) {
    u32 r;
    asm("v_cvt_pk_bf16_f32 %0, %1, %2" : "=v"(r) : "v"(lo), "v"(hi));
    return r;
}
__device__ __forceinline__ void gload16(const void* g, void* l) {
    __builtin_amdgcn_global_load_lds((const __attribute__((address_space(1))) void*)g,
                                     (__attribute__((address_space(3))) void*)l, 16, 0, 0);
}
#define VMCNT(n) asm volatile("s_waitcnt vmcnt(" #n ")" ::: "memory")

// ---------------------------------------------------------------------------
// Fused fp32->bf16 conversion for hs + Wq + Wk + Wv (contiguous dsts in ws).
// ---------------------------------------------------------------------------
struct us4 { u16 x, y, z, w; };
__global__ void cvt_all(const float* __restrict__ hs, const float* __restrict__ wq,
                        const float* __restrict__ wk, const float* __restrict__ wv,
                        u16* __restrict__ dst)
{
    int i = blockIdx.x * blockDim.x + threadIdx.x;
    const int stride = gridDim.x * blockDim.x;
    us4* d4 = (us4*)dst;
    for (; i < 1835008; i += stride) {
        const float4* s4;
        int j = i;
        if (j < 1048576)      { s4 = (const float4*)hs; }
        else if (j < 1310720) { s4 = (const float4*)wq; j -= 1048576; }
        else if (j < 1572864) { s4 = (const float4*)wk; j -= 1310720; }
        else                  { s4 = (const float4*)wv; j -= 1572864; }
        float4 v = s4[j];
        us4 o;
        o.x = f2bf(v.x); o.y = f2bf(v.y); o.z = f2bf(v.z); o.w = f2bf(v.w);
        d4[i] = o;
    }
}

// ---------------------------------------------------------------------------
// Kernel 1: fused QKV projection.  64x128 tile, BK=64, grid (24,64):
// blockIdx.x = mat*8+cb FASTEST so XCD r gets cb==r -> W slice 0.75 MB
// L2-resident (was: W 6 MB replicated across XCDs).  Q,K out [b,h,n,d];
// V out transposed.
// ---------------------------------------------------------------------------
__global__ __launch_bounds__(256) void qkv_gemm(
    const u16* __restrict__ hs,
    const u16* __restrict__ Wq, const u16* __restrict__ Wk, const u16* __restrict__ Wv,
    const float* __restrict__ bq, const float* __restrict__ bk, const float* __restrict__ bv,
    u16* __restrict__ oq, u16* __restrict__ ok, u16* __restrict__ ovt)
{
    __shared__ u16 smem[12288];        // sA 64x64 [0,4096), sB 128x64 [4096,12288)
    u16* sA = smem;
    u16* sB = smem + 4096;

    const int tid  = threadIdx.x;
    const int lane = tid & 63;
    const int wv_  = tid >> 6;
    const int c15  = lane & 15;
    const int q4   = lane >> 4;
    const int rb   = blockIdx.y;        // row block 0..63 (64 rows)
    const int mat  = blockIdx.x >> 3;   // 0=q 1=k 2=v
    const int cb   = blockIdx.x & 7;    // col block 0..7 (128 cols)

    const u16*   W    = (mat == 0) ? Wq : (mat == 1 ? Wk : Wv);
    const float* bias = (mat == 0) ? bq : (mat == 1 ? bk : bv);

    f32x4 acc[4][2] = {};

    int rA[2], cA[2], rB[4], cB[4];
#pragma unroll
    for (int p = 0; p < 2; ++p) {
        const int ch = p * 256 + tid;
        rA[p] = ch >> 3; cA[p] = ((ch & 7) ^ (rA[p] & 7)) * 8;
    }
#pragma unroll
    for (int p = 0; p < 4; ++p) {
        const int ch = p * 256 + tid;
        rB[p] = ch >> 3; cB[p] = ((ch & 7) ^ (rB[p] & 7)) * 8;
    }
    const u16* gA = hs + (rb * 64) * 1024;
    const u16* gB = W + (cb * 128) * 1024;
    const int swz = c15 & 7;

    for (int kb = 0; kb < 1024; kb += 64) {
        __syncthreads();
#pragma unroll
        for (int p = 0; p < 2; ++p)
            gload16(gA + rA[p] * 1024 + kb + cA[p], sA + (p * 256 + wv_ * 64) * 8);
#pragma unroll
        for (int p = 0; p < 4; ++p)
            gload16(gB + rB[p] * 1024 + kb + cB[p], sB + (p * 256 + wv_ * 64) * 8);
        __syncthreads();

#pragma unroll
        for (int kk = 0; kk < 2; ++kk) {
            const int cpos = ((kk * 4 + q4) ^ swz) * 8;
            bf16x8 af[4], bf[2];
#pragma unroll
            for (int mt = 0; mt < 4; ++mt)
                af[mt] = *(const bf16x8*)(sA + (mt * 16 + c15) * 64 + cpos);
#pragma unroll
            for (int nt = 0; nt < 2; ++nt)
                bf[nt] = *(const bf16x8*)(sB + (wv_ * 32 + nt * 16 + c15) * 64 + cpos);
#pragma unroll
            for (int mt = 0; mt < 4; ++mt)
#pragma unroll
                for (int nt = 0; nt < 2; ++nt)
                    acc[mt][nt] = __builtin_amdgcn_mfma_f32_16x16x32_bf16(
                        af[mt], bf[nt], acc[mt][nt], 0, 0, 0);
        }
    }

    // ---- epilogue: bias add, per-wave LDS transpose, coalesced 16B stores ----
    __syncthreads();
    const int hcol = cb * 2 + (wv_ >> 1);
    const int dbase = (wv_ & 1) * 32;
    float bvv[2];
#pragma unroll
    for (int nt = 0; nt < 2; ++nt)
        bvv[nt] = bias[cb * 128 + wv_ * 32 + nt * 16 + c15];

    u16* sc = smem + wv_ * 2560;
    if (mat != 2) {
        u16* dst = (mat == 0) ? oq : ok;
#pragma unroll
        for (int mt = 0; mt < 4; ++mt)
#pragma unroll
            for (int nt = 0; nt < 2; ++nt)
#pragma unroll
                for (int r = 0; r < 4; ++r)
                    sc[(mt * 16 + q4 * 4 + r) * 40 + nt * 16 + c15] =
                        f2bf(acc[mt][nt][r] + bvv[nt]);
#pragma unroll
        for (int i = 0; i < 4; ++i) {
            const int rl = i * 16 + (lane >> 2);
            const int c0 = (lane & 3) * 8;
            bf16x8 vv = *(const bf16x8*)(sc + rl * 40 + c0);
            const int n = rb * 64 + rl;
            const int bb = n >> 11, nn = n & 2047;
            *(bf16x8*)(dst + (((bb * 16 + hcol) * 2048) + nn) * 64 + dbase + c0) = vv;
        }
    } else {
#pragma unroll
        for (int mt = 0; mt < 4; ++mt)
#pragma unroll
            for (int nt = 0; nt < 2; ++nt)
#pragma unroll
                for (int r = 0; r < 4; ++r)
                    sc[(nt * 16 + c15) * 72 + mt * 16 + q4 * 4 + r] =
                        f2bf(acc[mt][nt][r] + bvv[nt]);
#pragma unroll
        for (int i = 0; i < 4; ++i) {
            const int dp = i * 8 + (lane >> 3);
            const int nl = (lane & 7) * 8;
            bf16x8 vv = *(const bf16x8*)(sc + dp * 72 + nl);
            const int n = rb * 64 + nl;
            const int bb = n >> 11, nn = n & 2047;
            *(bf16x8*)(ovt + (((bb * 16 + hcol) * 64) + dbase + dp) * 2048 + nn) = vv;
        }
    }
}

// ---------------------------------------------------------------------------
// Kernel 2: flash attention, S^T formulation, in-register P, FULL-K32 PV.
// R4 = R3 with the staging LDS stride bug fixed (p*2048, was p*4096 -> OOB
// writes corrupted neighboring buffers -> NaN).
// R3 design (counters-driven): R2 showed MfmaUtil 20%, VALU 34%, conflicts 0,
// FETCH 69.7 MB vs ~25 MB compulsory -> K/V replicated into all 8 XCD L2s,
// spilling to L3/HBM; with 2 waves/SIMD the load latency was exposed.
//   * XCD-aware grid: bh = blockIdx.x (fastest).  id%8 = bh%8, so XCD r owns
//     bh = r mod 8: K+V footprint 4 bh x 512 KB = 2 MB, L2-RESIDENT.  All
//     16 qt re-reads become L2 hits.
//   * KVBLK=128 staging (16 rounds), distance-2 prefetch, counted vmcnt:
//     2 buffers x (K 16KB + V 16KB) = 64 KB LDS; main loop waits
//     s_waitcnt vmcnt(8) (tile-T loads issued 2 iterations ago) + raw
//     s_barrier -- NEVER vmcnt(0) until the 2 peeled last iterations.
//     stage(T+2) goes after the read-done barrier (WAR-safe).  In-order
//     vmcnt retirement makes the in-loop mask loads safe: they only tighten
//     the wait, never loosen it.
//   * s_setprio(1) around MFMA clusters (T5).
// Per wave-iter (128 keys): 32 ds_read_b128, 64 MFMA, 64 exp2.
// ---------------------------------------------------------------------------
__global__ __launch_bounds__(256, 2) void attn(
    const u16* __restrict__ qm, const u16* __restrict__ km, const u16* __restrict__ vtm,
    const float* __restrict__ mask, float* __restrict__ out)
{
    __shared__ u16 sK0[8192];          // K tile: 128 perm-key rows x 64 d
    __shared__ u16 sV0[8192];          // V^T tile: 64 d rows x 128 keys
    __shared__ u16 sK1[8192];
    __shared__ u16 sV1[8192];

    const int tid = threadIdx.x, lane = tid & 63, w = tid >> 6;
    const int c15 = lane & 15, q4 = lane >> 4;
    const int bh = blockIdx.x;         // 0..31 FASTEST -> XCD locality
    const int qt = blockIdx.y;         // q tile 0..15 (128 rows each)
    const int b = bh >> 4;

    // Q fragments (B operand of S^T = K.Q^T): rows qt*128 + w*32 + rt*16 + c15
    bf16x8 qf[2][2];
    const u16* qbase = qm + (bh * 2048 + qt * 128 + w * 32) * 64;
#pragma unroll
    for (int rt = 0; rt < 2; ++rt)
#pragma unroll
        for (int kt = 0; kt < 2; ++kt)
            qf[rt][kt] = *(const bf16x8*)(qbase + (rt * 16 + c15) * 64 + kt * 32 + q4 * 8);

    float l_acc[2] = {0.f, 0.f};
    f32x4 accO[2][4] = {};

    const u16* kbase  = km  + bh * 2048 * 64;
    const u16* vtbase = vtm + bh * 64 * 2048;   // [d][n]

    // K staging: 1024 chunks, 4/thread.  chunk c=p*256+tid -> LDS offset
    // 2048p + 8*tid = row(32p + tid>>3)*64 + (tid&7)*8; src key perm'd.
    const int rK   = tid >> 3;
    const int colK = ((tid & 7) ^ (rK & 7)) * 8;
    const int prK  = (rK & 3) | ((rK & 0x0C) << 1) | ((rK & 0x10) >> 2);
    // V staging: chunk c -> LDS offset 2048p + 8*tid = row(16p + tid>>4)*128
    // + (tid&15)*8; XOR-swizzle (tid&15) ^ (d&7).
    const int rV   = tid >> 4;
    const int colV = ((tid & 15) ^ (rV & 7)) * 8;
    const int ldsW = w * 512;                   // wave-uniform LDS dest offset

    const float* mbase = mask + b * 2048 + 8 * q4;

    auto stage = [&](u16* dK, u16* dV, int TT) {
        const u16* kg = kbase + TT * 128 * 64;
        const u16* vg = vtbase + TT * 128;
#pragma unroll
        for (int p = 0; p < 4; ++p)
            gload16(kg + (prK + 32 * p) * 64 + colK, dK + p * 2048 + ldsW);
#pragma unroll
        for (int p = 0; p < 4; ++p)
            gload16(vg + (rV + 16 * p) * 2048 + colV, dV + p * 2048 + ldsW);
    };

    // ---- compute one 64-key half from the given buffers ----
    //   sKh = K buffer + h*64 rows; pcBase = h*8 (V key-chunk offset);
    //   kb = global key base of this half.
    auto compute64 = [&](const u16* sKh, const u16* sVb, int pcBase, int kb) {
        // mask per key, pre-scaled by log2e.  (t,rr) <-> real key
        // kb + 32*(t>>1) + 8*q4 + 4*(t&1) + rr  (aligned float4 per t).
        float mkv[4][4];
#pragma unroll
        for (int t = 0; t < 4; ++t) {
            float4 m4 = *(const float4*)(mbase + kb + 32 * (t >> 1) + 4 * (t & 1));
            mkv[t][0] = m4.x * 1.4426950408889634f;
            mkv[t][1] = m4.y * 1.4426950408889634f;
            mkv[t][2] = m4.z * 1.4426950408889634f;
            mkv[t][3] = m4.w * 1.4426950408889634f;
        }

        // --- S^T = K Q^T: lane(q4,c15) reg rr = S[rho=t*16+q4*4+rr][rt*16+c15]
        f32x4 accST[4][2] = {};
        __builtin_amdgcn_s_setprio(1);
#pragma unroll
        for (int kt = 0; kt < 2; ++kt) {
            bf16x8 kf[4];
#pragma unroll
            for (int t = 0; t < 4; ++t) {
                const int cpos = (kt * 4 + q4) ^ (c15 & 7);
                kf[t] = *(const bf16x8*)(sKh + (t * 16 + c15) * 64 + cpos * 8);
            }
#pragma unroll
            for (int t = 0; t < 4; ++t)
#pragma unroll
                for (int rt = 0; rt < 2; ++rt)
                    accST[t][rt] = __builtin_amdgcn_mfma_f32_16x16x32_bf16(
                        kf[t], qf[rt][kt], accST[t][rt], 0, 0, 0);
        }
        __builtin_amdgcn_s_setprio(0);

        // --- softmax in-register: p = exp2(s*0.125*log2e + m*log2e)
        u32 pu[4][2][2];
#pragma unroll
        for (int t = 0; t < 4; ++t)
#pragma unroll
            for (int rt = 0; rt < 2; ++rt) {
                float p[4];
#pragma unroll
                for (int rr = 0; rr < 4; ++rr) {
                    p[rr] = __builtin_amdgcn_exp2f(
                        fmaf(accST[t][rt][rr], 0.18033688011112042f, mkv[t][rr]));
                    l_acc[rt] += p[rr];
                }
                pu[t][rt][0] = cvt_pk_bf16(p[0], p[1]);
                pu[t][rt][1] = cvt_pk_bf16(p[2], p[3]);
            }

        // --- PV full-K32: A-frag of lane-group q4 = real keys 32g+8q4..+7
        __builtin_amdgcn_s_setprio(1);
#pragma unroll
        for (int g = 0; g < 2; ++g) {
            // B-frags shared across rt: V[keys 32g+8q4..+7][d=nt*16+c15]
            bf16x8 vB[4];
#pragma unroll
            for (int nt = 0; nt < 4; ++nt) {
                const int d = nt * 16 + c15;
                const int pc = pcBase + ((4 * g + q4) ^ (d & 7));
                vB[nt] = *(const bf16x8*)(sVb + d * 128 + pc * 8);
            }
#pragma unroll
            for (int rt = 0; rt < 2; ++rt) {
                union { bf16x8 v; u32 u[4]; } ta;
                ta.u[0] = pu[2 * g][rt][0];
                ta.u[1] = pu[2 * g][rt][1];
                ta.u[2] = pu[2 * g + 1][rt][0];
                ta.u[3] = pu[2 * g + 1][rt][1];
#pragma unroll
                for (int nt = 0; nt < 4; ++nt)
                    accO[rt][nt] = __builtin_amdgcn_mfma_f32_16x16x32_bf16(
                        ta.v, vB[nt], accO[rt][nt], 0, 0, 0);
            }
        }
        __builtin_amdgcn_s_setprio(0);
    };

    // ---- prologue: tiles 0,1 in flight (16 loads/thread) ----
    stage(sK0, sV0, 0);
    stage(sK1, sV1, 1);

    // ---- main loop: T=0..13 (unroll 2), stage T+2 / T+3; peel 14,15 ----
#pragma unroll 1
    for (int T = 0; T < 14; T += 2) {
        VMCNT(8);                              // own tile-T loads landed
        __builtin_amdgcn_s_barrier();          // everyone's tile-T writes landed
        __builtin_amdgcn_sched_barrier(0);
        compute64(sK0, sV0, 0, T * 128);
        compute64(sK0 + 64 * 64, sV0, 8, T * 128 + 64);
        __builtin_amdgcn_s_barrier();          // all waves done reading buf0
        __builtin_amdgcn_sched_barrier(0);
        stage(sK0, sV0, T + 2);

        VMCNT(8);                              // tile T+1 landed
        __builtin_amdgcn_s_barrier();
        __builtin_amdgcn_sched_barrier(0);
        compute64(sK1, sV1, 0, (T + 1) * 128);
        compute64(sK1 + 64 * 64, sV1, 8, (T + 1) * 128 + 64);
        __builtin_amdgcn_s_barrier();          // all waves done reading buf1
        __builtin_amdgcn_sched_barrier(0);
        stage(sK1, sV1, T + 3);
    }
    // T=14 (buf0): outstanding = {S14,S15} -> wait 8
    VMCNT(8);
    __builtin_amdgcn_s_barrier();
    __builtin_amdgcn_sched_barrier(0);
    compute64(sK0, sV0, 0, 14 * 128);
    compute64(sK0 + 64 * 64, sV0, 8, 14 * 128 + 64);
    // T=15 (buf1): outstanding = {S15} -> wait 0
    VMCNT(0);
    __builtin_amdgcn_s_barrier();
    __builtin_amdgcn_sched_barrier(0);
    compute64(sK1, sV1, 0, 15 * 128);
    compute64(sK1 + 64 * 64, sV1, 8, 15 * 128 + 64);

    // --- l reduction across q4 groups -> total per qrow=c15
#pragma unroll
    for (int rt = 0; rt < 2; ++rt) {
        l_acc[rt] += __shfl_xor(l_acc[rt], 16);
        l_acc[rt] += __shfl_xor(l_acc[rt], 32);
    }

    // --- epilogue: accO C-layout row=q4*4+rr, col=c15=d
    const int h = bh & 15;
#pragma unroll
    for (int rt = 0; rt < 2; ++rt) {
        float inv[4];
#pragma unroll
        for (int rr = 0; rr < 4; ++rr)
            inv[rr] = 1.0f / __shfl(l_acc[rt], q4 * 4 + rr);
#pragma unroll
        for (int nt = 0; nt < 4; ++nt)
#pragma unroll
            for (int rr = 0; rr < 4; ++rr) {
                const int qrow = qt * 128 + w * 32 + rt * 16 + q4 * 4 + rr;
                const int d = nt * 16 + c15;
                out[(b * 2048 + qrow) * 1024 + h * 64 + d] = accO[rt][nt][rr] * inv[rr];
            }
    }
}

// ---------------------------------------------------------------------------
extern "C" void kernel_launch(void* const* d_in, const int* in_sizes, int n_in,
                              void* d_out, int out_size, void* d_ws, size_t ws_size,
                              hipStream_t stream)
{
    const float* hs   = (const float*)d_in[0];
    const float* mask = (const float*)d_in[1];
    const float* Wq   = (const float*)d_in[2];
    const float* bq   = (const float*)d_in[3];
    const float* Wk   = (const float*)d_in[4];
    const float* bk   = (const float*)d_in[5];
    const float* Wv   = (const float*)d_in[6];
    const float* bv   = (const float*)d_in[7];

    // workspace layout (u16 units)
    u16* ws   = (u16*)d_ws;
    u16* qw   = ws;                     // Q  [b,h,n,d] bf16
    u16* kw   = ws + 4194304;           // K  [b,h,n,d]
    u16* vtw  = ws + 8388608;           // V^T [b,h,d,n]
    u16* hsb  = ws + 12582912;          // hidden_states bf16 (cvt_all dst start)
    u16* wqb  = ws + 16777216;
    u16* wkb  = ws + 17825792;
    u16* wvb  = ws + 18874368;

    cvt_all<<<1024, 256, 0, stream>>>(hs, Wq, Wk, Wv, hsb);

    qkv_gemm<<<dim3(24, 64), 256, 0, stream>>>(hsb, wqb, wkb, wvb, bq, bk, bv, qw, kw, vtw);
    attn<<<dim3(32, 16), 256, 0, stream>>>(qw, kw, vtw, mask, (float*)d_out);
}